// Round 11
// baseline (907.207 us; speedup 1.0000x reference)
//
#include <hip/hip_runtime.h>
#include <hip/hip_bf16.h>
#include <hip/hip_fp16.h>
#include <hip/hip_cooperative_groups.h>

namespace cg = cooperative_groups;

// ---------------- problem constants (match reference) ----------------
constexpr int N_NODES  = 50000;
constexpr int N_EDGES  = 800000;
constexpr int F_HID    = 128;
constexpr int N_GRAPHS = 64;
constexpr float BN_EPS = 1e-5f;
constexpr int ROW_CAP  = 64;   // fixed CSR row capacity; deg ~ Poisson(16)
constexpr int STATS_G  = 16;   // column-stats partial groups

using short8  = __attribute__((ext_vector_type(8))) short;
using float4v = __attribute__((ext_vector_type(4))) float;
using float2v = __attribute__((ext_vector_type(2))) float;
using uint4v  = __attribute__((ext_vector_type(4))) uint;

__device__ __forceinline__ ushort f2bf(float f) {
    uint u = __float_as_uint(f);
    return (ushort)((u + 0x7fffu + ((u >> 16) & 1u)) >> 16);   // RNE
}
__device__ __forceinline__ float bflo(uint u) { return __uint_as_float(u << 16); }
__device__ __forceinline__ float bfhi(uint u) { return __uint_as_float(u & 0xffff0000u); }
__device__ __forceinline__ int sidx(int c) { return c ^ (c >> 4); }

__device__ __forceinline__ float2v unpk(uint u) {
    float2v r;
    r.x = __uint_as_float(u << 16);
    r.y = __uint_as_float(u & 0xffff0000u);
    return r;
}
__device__ __forceinline__ void pk_add(float2v &a, float2v b) {
    asm("v_pk_add_f32 %0, %1, %0" : "+v"(a) : "v"(b));
}
__device__ __forceinline__ void pk_fma(float2v &a, float2v v, float2v w) {
    asm("v_pk_fma_f32 %0, %1, %2, %0" : "+v"(a) : "v"(v), "v"(w));
}

#define SUMV(vv) \
    pk_add(a01, unpk((vv).x)); pk_add(a23, unpk((vv).y)); \
    pk_add(a45, unpk((vv).z)); pk_add(a67, unpk((vv).w));

#define ACCV(vv, w2) \
    pk_fma(a01, unpk((vv).x), w2); pk_fma(a23, unpk((vv).y), w2); \
    pk_fma(a45, unpk((vv).z), w2); pk_fma(a67, unpk((vv).w), w2);

// ---------------- grid geometry ----------------
constexpr int CONVW_ELEMS  = 96 * 128 + 2 * 128 * 128;                 // 45056
constexpr int CONVW_BLOCKS = (CONVW_ELEMS + 128 + 255) / 256;          // 177
// zero region layout MUST match host alloc order/padding (256B aligned each):
// cnt(200192B) | part1(16384) | part2(16384) | part3(16384) | pooled(32768)
constexpr int ZWORDS    = (200192 + 3 * 16384 + 32768) / 4;            // 70528
constexpr int ZB_BLOCKS = (ZWORDS + 255) / 256;                        // 276
constexpr int P0_BLOCKS = CONVW_BLOCKS + ZB_BLOCKS;                    // 453
constexpr int GEMM1_BLOCKS = (N_NODES + 63) / 64;       // 782
constexpr int FILL_SLABS   = (N_EDGES + 1023) / 1024;   // 782
constexpr int FILL_BLOCKS  = FILL_SLABS * 8;            // 6256
constexpr int P1_BLOCKS    = GEMM1_BLOCKS + FILL_BLOCKS;// 7038
constexpr int AGG_BLOCKS   = N_NODES / 4;               // 12500
constexpr int POOL_ROWS    = 128;
constexpr int POOL_BLOCKS  = (N_NODES + POOL_ROWS - 1) / POOL_ROWS;    // 391

// ================= phase bodies (verified R9 kernels, returns -> guards) =================

__device__ void body_prep(int vb, const float* __restrict__ W1, const float* __restrict__ W2,
                          const float* __restrict__ W3, ushort* __restrict__ W1t,
                          ushort* __restrict__ W2t, ushort* __restrict__ W3t,
                          ushort* __restrict__ hbA, uint* __restrict__ zbase) {
    if (vb < CONVW_BLOCKS) {
        int i = vb * 256 + threadIdx.x;
        constexpr int S1 = 96 * 128, S2 = S1 + 128 * 128, S3 = S2 + 128 * 128;
        if (i < S1) {
            int n = i & 127, k = i >> 7;
            W1t[n * 96 + k] = f2bf(W1[i]);
        } else if (i < S2) {
            int j = i - S1, n = j & 127, k = j >> 7;
            W2t[n * 128 + k] = f2bf(W2[j]);
        } else if (i < S3) {
            int j = i - S2, n = j & 127, k = j >> 7;
            W3t[n * 128 + k] = f2bf(W3[j]);
        } else if (i < S3 + 128) {
            hbA[(size_t)N_NODES * F_HID + (i - S3)] = 0;   // zero row for masked gathers
        }
    } else {
        int j = (vb - CONVW_BLOCKS) * 256 + (int)threadIdx.x;
        if (j < ZWORDS) zbase[j] = 0;
    }
}

__device__ void body_fillgemm(int vb, const int* __restrict__ ei,
                              int* __restrict__ cnt, ushort* __restrict__ col,
                              const float* __restrict__ X, const ushort* __restrict__ Wt,
                              ushort* __restrict__ C) {
    if (vb < GEMM1_BLOCKS) {
        constexpr int K = 96, KSTEPS = 3;
        int wave = threadIdx.x >> 6, lane = threadIdx.x & 63;
        int m = lane & 15, quad = lane >> 4;
        int row_base = vb * 64 + wave * 16;
        short8 afrag[KSTEPS];
        int arow = min(row_base + m, N_NODES - 1);
#pragma unroll
        for (int ks = 0; ks < KSTEPS; ks++) {
            const float* src = X + (size_t)arow * K + ks * 32 + quad * 8;
            float4 a0 = *(const float4*)src;
            float4 a1 = *(const float4*)(src + 4);
            afrag[ks][0] = (short)f2bf(a0.x); afrag[ks][1] = (short)f2bf(a0.y);
            afrag[ks][2] = (short)f2bf(a0.z); afrag[ks][3] = (short)f2bf(a0.w);
            afrag[ks][4] = (short)f2bf(a1.x); afrag[ks][5] = (short)f2bf(a1.y);
            afrag[ks][6] = (short)f2bf(a1.z); afrag[ks][7] = (short)f2bf(a1.w);
        }
#pragma unroll
        for (int nt = 0; nt < 8; nt++) {
            float4v acc = {0.f, 0.f, 0.f, 0.f};
            const ushort* wbase = Wt + (size_t)(nt * 16 + m) * K + quad * 8;
#pragma unroll
            for (int ks = 0; ks < KSTEPS; ks++) {
                short8 bfrag = *(const short8*)(wbase + ks * 32);
                acc = __builtin_amdgcn_mfma_f32_16x16x32_bf16(afrag[ks], bfrag, acc, 0, 0, 0);
            }
            int colg = nt * 16 + m;
#pragma unroll
            for (int r = 0; r < 4; r++) {
                int rowg = row_base + quad * 4 + r;
                if (rowg < N_NODES) C[(size_t)rowg * F_HID + colg] = f2bf(acc[r]);
            }
        }
    } else {
        // color = vb&7 matches XCD round-robin; preserved in grid-stride since grid%8==0
        int fb    = vb - GEMM1_BLOCKS;
        int color = vb & 7;
        int slab  = fb >> 3;
        int i0 = slab * 1024 + threadIdx.x * 4;
        if (i0 < N_EDGES) {
            int4 dv = *(const int4*)(ei + N_EDGES + i0);
            int4 sv = *(const int4*)(ei + i0);
#pragma unroll
            for (int k = 0; k < 4; k++) {
                int d = (&dv.x)[k];
                if ((d & 7) != color) continue;
                int s = (&sv.x)[k];
                int pos = atomicAdd(&cnt[d], 1);
                if (pos < ROW_CAP) col[(size_t)d * ROW_CAP + pos] = (ushort)s;
            }
        }
    }
}

__device__ void body_gemm_bn(int vb, const ushort* __restrict__ A, const float* __restrict__ part,
                             const float* __restrict__ gam, const float* __restrict__ bet,
                             const ushort* __restrict__ Wt, const int* __restrict__ cnt,
                             ushort* __restrict__ C) {
    __shared__ float cs_sh[256];
    {
        int t = threadIdx.x;
        float v = 0.f;
#pragma unroll
        for (int g2 = 0; g2 < STATS_G; g2++) v += part[g2 * 256 + sidx(t & 127) + (t & 128)];
        cs_sh[t] = v;
    }
    __syncthreads();

    constexpr int K = 128, KSTEPS = 4;
    int wave = threadIdx.x >> 6, lane = threadIdx.x & 63;
    int m = lane & 15, quad = lane >> 4;
    int row_base = vb * 64 + wave * 16;
    int arow = min(row_base + m, N_NODES - 1);
    constexpr float invN = 1.0f / N_NODES;

    float dinv4[4];
#pragma unroll
    for (int r = 0; r < 4; r++) {
        int rg = min(row_base + quad * 4 + r, N_NODES - 1);
        dinv4[r] = rsqrtf((float)(cnt[rg] + 1));
    }

    short8 afrag[KSTEPS];
#pragma unroll
    for (int ks = 0; ks < KSTEPS; ks++) {
        int k0 = ks * 32 + quad * 8;
        uint4 av = *(const uint4*)(A + (size_t)arow * K + k0);
        float vals[8] = {bflo(av.x), bfhi(av.x), bflo(av.y), bfhi(av.y),
                         bflo(av.z), bfhi(av.z), bflo(av.w), bfhi(av.w)};
#pragma unroll
        for (int jj = 0; jj < 8; jj += 4) {
            float4 gv = *(const float4*)(gam + k0 + jj);
            float4 bv = *(const float4*)(bet + k0 + jj);
            const float* g = (const float*)&gv; const float* b = (const float*)&bv;
#pragma unroll
            for (int t = 0; t < 4; t++) {
                int kc = k0 + jj + t;
                float mean = cs_sh[kc] * invN;
                float var  = cs_sh[128 + kc] * invN - mean * mean;
                float sc   = g[t] * rsqrtf(var + BN_EPS);
                float val  = fmaxf((vals[jj + t] - mean) * sc + b[t], 0.0f);
                afrag[ks][jj + t] = (short)f2bf(val);
            }
        }
    }

#pragma unroll
    for (int nt = 0; nt < 8; nt++) {
        float4v acc = {0.f, 0.f, 0.f, 0.f};
        const ushort* wbase = Wt + (size_t)(nt * 16 + m) * K + quad * 8;
#pragma unroll
        for (int ks = 0; ks < KSTEPS; ks++) {
            short8 bfrag = *(const short8*)(wbase + ks * 32);
            acc = __builtin_amdgcn_mfma_f32_16x16x32_bf16(afrag[ks], bfrag, acc, 0, 0, 0);
        }
        int colg = nt * 16 + m;
#pragma unroll
        for (int r = 0; r < 4; r++) {
            int rowg = row_base + quad * 4 + r;
            if (rowg < N_NODES) C[(size_t)rowg * F_HID + colg] = f2bf(acc[r] * dinv4[r]);
        }
    }
    __syncthreads();   // loop-reuse guard for cs_sh (grid-stride iterations)
}

template<bool PRESCALED>
__device__ void body_aggregate(int vb, const ushort* __restrict__ h, const int* __restrict__ cnt,
                               const ushort* __restrict__ col, ushort* __restrict__ outp,
                               float* __restrict__ part) {
    __shared__ float sh_s[4][128];
    __shared__ float sh_q[4][128];
    int wv   = (vb * 256 + (int)threadIdx.x) >> 6;
    int wave = threadIdx.x >> 6;
    int lane = threadIdx.x & 63;
    int q  = lane >> 4;
    int sl = lane & 15;
    const ushort* crow = col + (size_t)wv * ROW_CAP;
    constexpr int ZR = N_NODES;

    int deg = cnt[wv];
    uint4 R0 = *(const uint4*)(crow);
    uint4 R1 = *(const uint4*)(crow + 8);
    uint4 R2 = *(const uint4*)(crow + 16);
    uint4 R3 = *(const uint4*)(crow + 24);
    uint4 selfv = *(const uint4*)(h + (size_t)wv * F_HID + sl * 8);

    int len = min(deg, ROW_CAP);
    float dinv_d = rsqrtf((float)(deg + 1));
    float2v a01 = {0.f, 0.f}, a23 = {0.f, 0.f}, a45 = {0.f, 0.f}, a67 = {0.f, 0.f};

    if (len <= 32) {
        int  sh16 = (q & 1) << 4;
        bool qhi  = (q & 2) != 0;
        uint pp0 = qhi ? R0.y : R0.x;  uint pp1 = qhi ? R0.w : R0.z;
        uint pp2 = qhi ? R1.y : R1.x;  uint pp3 = qhi ? R1.w : R1.z;
        uint pp4 = qhi ? R2.y : R2.x;  uint pp5 = qhi ? R2.w : R2.z;
        uint pp6 = qhi ? R3.y : R3.x;  uint pp7 = qhi ? R3.w : R3.z;
        int rec0 = (int)((pp0 >> sh16) & 0xffffu);
        int rec1 = (int)((pp1 >> sh16) & 0xffffu);
        int rec2 = (int)((pp2 >> sh16) & 0xffffu);
        int rec3 = (int)((pp3 >> sh16) & 0xffffu);
        int rec4 = (int)((pp4 >> sh16) & 0xffffu);
        int rec5 = (int)((pp5 >> sh16) & 0xffffu);
        int rec6 = (int)((pp6 >> sh16) & 0xffffu);
        int rec7 = (int)((pp7 >> sh16) & 0xffffu);
        int r0 = (q      < len) ? rec0 : ZR;
        int r1 = (q + 4  < len) ? rec1 : ZR;
        int r2 = (q + 8  < len) ? rec2 : ZR;
        int r3 = (q + 12 < len) ? rec3 : ZR;
        int r4 = (q + 16 < len) ? rec4 : ZR;
        int r5 = (q + 20 < len) ? rec5 : ZR;
        int r6 = (q + 24 < len) ? rec6 : ZR;
        int r7 = (q + 28 < len) ? rec7 : ZR;
        uint4v v0 = *(const uint4v*)(h + (size_t)r0 * F_HID + sl * 8);
        uint4v v1 = *(const uint4v*)(h + (size_t)r1 * F_HID + sl * 8);
        uint4v v2 = *(const uint4v*)(h + (size_t)r2 * F_HID + sl * 8);
        uint4v v3 = *(const uint4v*)(h + (size_t)r3 * F_HID + sl * 8);
        uint4v v4 = *(const uint4v*)(h + (size_t)r4 * F_HID + sl * 8);
        uint4v v5 = *(const uint4v*)(h + (size_t)r5 * F_HID + sl * 8);
        uint4v v6 = *(const uint4v*)(h + (size_t)r6 * F_HID + sl * 8);
        uint4v v7 = *(const uint4v*)(h + (size_t)r7 * F_HID + sl * 8);
        if constexpr (PRESCALED) {
            asm volatile("" : "+v"(v0), "+v"(v1), "+v"(v2), "+v"(v3));
            asm volatile("" : "+v"(v4), "+v"(v5), "+v"(v6), "+v"(v7));
            int slen = __builtin_amdgcn_readfirstlane(len);
            if (q == 0) { SUMV(selfv) }
            if (slen > 0)  { SUMV(v0) }
            if (slen > 4)  { SUMV(v1) }
            if (slen > 8)  { SUMV(v2) }
            if (slen > 12) { SUMV(v3) }
            if (slen > 16) { SUMV(v4) }
            if (slen > 20) { SUMV(v5) }
            if (slen > 24) { SUMV(v6) }
            if (slen > 28) { SUMV(v7) }
        } else {
            int c0 = cnt[r0]; int c1 = cnt[r1]; int c2 = cnt[r2]; int c3 = cnt[r3];
            int c4 = cnt[r4]; int c5 = cnt[r5]; int c6 = cnt[r6]; int c7 = cnt[r7];
            asm volatile("" : "+v"(v0), "+v"(v1), "+v"(v2), "+v"(v3));
            asm volatile("" : "+v"(v4), "+v"(v5), "+v"(v6), "+v"(v7));
            asm volatile("" : "+v"(c0), "+v"(c1), "+v"(c2), "+v"(c3),
                             "+v"(c4), "+v"(c5), "+v"(c6), "+v"(c7));
            int slen = __builtin_amdgcn_readfirstlane(len);
            if (q == 0) { float sw = dinv_d * dinv_d; float2v sw2 = {sw, sw}; ACCV(selfv, sw2) }
            if (slen > 0)  { float w = (q      < len) ? rsqrtf((float)(c0 + 1)) * dinv_d : 0.f; float2v w2 = {w, w}; ACCV(v0, w2) }
            if (slen > 4)  { float w = (q + 4  < len) ? rsqrtf((float)(c1 + 1)) * dinv_d : 0.f; float2v w2 = {w, w}; ACCV(v1, w2) }
            if (slen > 8)  { float w = (q + 8  < len) ? rsqrtf((float)(c2 + 1)) * dinv_d : 0.f; float2v w2 = {w, w}; ACCV(v2, w2) }
            if (slen > 12) { float w = (q + 12 < len) ? rsqrtf((float)(c3 + 1)) * dinv_d : 0.f; float2v w2 = {w, w}; ACCV(v3, w2) }
            if (slen > 16) { float w = (q + 16 < len) ? rsqrtf((float)(c4 + 1)) * dinv_d : 0.f; float2v w2 = {w, w}; ACCV(v4, w2) }
            if (slen > 20) { float w = (q + 20 < len) ? rsqrtf((float)(c5 + 1)) * dinv_d : 0.f; float2v w2 = {w, w}; ACCV(v5, w2) }
            if (slen > 24) { float w = (q + 24 < len) ? rsqrtf((float)(c6 + 1)) * dinv_d : 0.f; float2v w2 = {w, w}; ACCV(v6, w2) }
            if (slen > 28) { float w = (q + 28 < len) ? rsqrtf((float)(c7 + 1)) * dinv_d : 0.f; float2v w2 = {w, w}; ACCV(v7, w2) }
        }
    } else {
        if (PRESCALED) {
            if (q == 0) { SUMV(selfv) }
        } else if (q == 0) {
            float sw = dinv_d * dinv_d; float2v sw2 = {sw, sw}; ACCV(selfv, sw2)
        }
        int base = 0;
        for (; base + 16 <= len; base += 16) {
            int r0 = crow[base + q];
            int r1 = crow[base + 4 + q];
            int r2 = crow[base + 8 + q];
            int r3 = crow[base + 12 + q];
            uint4 v0 = *(const uint4*)(h + (size_t)r0 * F_HID + sl * 8);
            uint4 v1 = *(const uint4*)(h + (size_t)r1 * F_HID + sl * 8);
            uint4 v2 = *(const uint4*)(h + (size_t)r2 * F_HID + sl * 8);
            uint4 v3 = *(const uint4*)(h + (size_t)r3 * F_HID + sl * 8);
            if (PRESCALED) {
                SUMV(v0) SUMV(v1) SUMV(v2) SUMV(v3)
            } else {
                float w0 = rsqrtf((float)(cnt[r0] + 1)) * dinv_d;
                float w1 = rsqrtf((float)(cnt[r1] + 1)) * dinv_d;
                float w2 = rsqrtf((float)(cnt[r2] + 1)) * dinv_d;
                float w3 = rsqrtf((float)(cnt[r3] + 1)) * dinv_d;
                { float2v w2v = {w0, w0}; ACCV(v0, w2v) }
                { float2v w2v = {w1, w1}; ACCV(v1, w2v) }
                { float2v w2v = {w2, w2}; ACCV(v2, w2v) }
                { float2v w2v = {w3, w3}; ACCV(v3, w2v) }
            }
        }
        if (base < len) {
            int i0t = base + q, i1t = base + 4 + q, i2t = base + 8 + q, i3t = base + 12 + q;
            int r0 = (i0t < len) ? (int)crow[i0t] : ZR;
            int r1 = (i1t < len) ? (int)crow[i1t] : ZR;
            int r2 = (i2t < len) ? (int)crow[i2t] : ZR;
            int r3 = (i3t < len) ? (int)crow[i3t] : ZR;
            uint4 v0 = *(const uint4*)(h + (size_t)r0 * F_HID + sl * 8);
            uint4 v1 = *(const uint4*)(h + (size_t)r1 * F_HID + sl * 8);
            uint4 v2 = *(const uint4*)(h + (size_t)r2 * F_HID + sl * 8);
            uint4 v3 = *(const uint4*)(h + (size_t)r3 * F_HID + sl * 8);
            if (PRESCALED) {
                SUMV(v0) SUMV(v1) SUMV(v2) SUMV(v3)
            } else {
                float w0 = (i0t < len) ? rsqrtf((float)(cnt[r0] + 1)) * dinv_d : 0.f;
                float w1 = (i1t < len) ? rsqrtf((float)(cnt[r1] + 1)) * dinv_d : 0.f;
                float w2 = (i2t < len) ? rsqrtf((float)(cnt[r2] + 1)) * dinv_d : 0.f;
                float w3 = (i3t < len) ? rsqrtf((float)(cnt[r3] + 1)) * dinv_d : 0.f;
                { float2v w2v = {w0, w0}; ACCV(v0, w2v) }
                { float2v w2v = {w1, w1}; ACCV(v1, w2v) }
                { float2v w2v = {w2, w2}; ACCV(v2, w2v) }
                { float2v w2v = {w3, w3}; ACCV(v3, w2v) }
            }
        }
    }
    float a0 = a01.x, a1 = a01.y, a2 = a23.x, a3 = a23.y;
    float a4 = a45.x, a5 = a45.y, a6 = a67.x, a7 = a67.y;
    a0 += __shfl_down(a0, 16); a1 += __shfl_down(a1, 16); a2 += __shfl_down(a2, 16); a3 += __shfl_down(a3, 16);
    a4 += __shfl_down(a4, 16); a5 += __shfl_down(a5, 16); a6 += __shfl_down(a6, 16); a7 += __shfl_down(a7, 16);
    a0 += __shfl_down(a0, 32); a1 += __shfl_down(a1, 32); a2 += __shfl_down(a2, 32); a3 += __shfl_down(a3, 32);
    a4 += __shfl_down(a4, 32); a5 += __shfl_down(a5, 32); a6 += __shfl_down(a6, 32); a7 += __shfl_down(a7, 32);
    if (q == 0) {
        if (PRESCALED) {
            a0 *= dinv_d; a1 *= dinv_d; a2 *= dinv_d; a3 *= dinv_d;
            a4 *= dinv_d; a5 *= dinv_d; a6 *= dinv_d; a7 *= dinv_d;
        }
        uint4 o;
        o.x = (uint)f2bf(a0) | ((uint)f2bf(a1) << 16);
        o.y = (uint)f2bf(a2) | ((uint)f2bf(a3) << 16);
        o.z = (uint)f2bf(a4) | ((uint)f2bf(a5) << 16);
        o.w = (uint)f2bf(a6) | ((uint)f2bf(a7) << 16);
        *(uint4*)(outp + (size_t)wv * F_HID + sl * 8) = o;
        int c0 = sl * 8;
        sh_s[wave][sidx(c0 + 0)] = a0; sh_q[wave][sidx(c0 + 0)] = a0 * a0;
        sh_s[wave][sidx(c0 + 1)] = a1; sh_q[wave][sidx(c0 + 1)] = a1 * a1;
        sh_s[wave][sidx(c0 + 2)] = a2; sh_q[wave][sidx(c0 + 2)] = a2 * a2;
        sh_s[wave][sidx(c0 + 3)] = a3; sh_q[wave][sidx(c0 + 3)] = a3 * a3;
        sh_s[wave][sidx(c0 + 4)] = a4; sh_q[wave][sidx(c0 + 4)] = a4 * a4;
        sh_s[wave][sidx(c0 + 5)] = a5; sh_q[wave][sidx(c0 + 5)] = a5 * a5;
        sh_s[wave][sidx(c0 + 6)] = a6; sh_q[wave][sidx(c0 + 6)] = a6 * a6;
        sh_s[wave][sidx(c0 + 7)] = a7; sh_q[wave][sidx(c0 + 7)] = a7 * a7;
    }
    __syncthreads();
    int t = threadIdx.x;
    int cc = sidx(t & 127);
    float v = (t < 128) ? (sh_s[0][cc] + sh_s[1][cc] + sh_s[2][cc] + sh_s[3][cc])
                        : (sh_q[0][cc] + sh_q[1][cc] + sh_q[2][cc] + sh_q[3][cc]);
    atomicAdd(&part[(vb & (STATS_G - 1)) * 256 + (t & 128) + cc], v);
    __syncthreads();   // loop-reuse guard for sh_s/sh_q (grid-stride iterations)
}

__device__ void body_pool(int vb, const ushort* __restrict__ h, const float* __restrict__ part,
                          const float* __restrict__ gam, const float* __restrict__ bet,
                          const int* __restrict__ batch, float* __restrict__ pooled_sum) {
    __shared__ float cs_sh[256];
    __shared__ int sbatch[POOL_ROWS];
    int row0 = vb * POOL_ROWS;
    {
        int t = threadIdx.x;
        float v = 0.f;
#pragma unroll
        for (int g2 = 0; g2 < STATS_G; g2++) v += part[g2 * 256 + sidx(t & 127) + (t & 128)];
        cs_sh[t] = v;
    }
    if (threadIdx.x < POOL_ROWS) {
        int r = row0 + threadIdx.x;
        sbatch[threadIdx.x] = (r < N_NODES) ? batch[r] : -1;
    }
    __syncthreads();
    int c4 = (threadIdx.x & 31) * 4;
    int stripe = threadIdx.x >> 5;
    int nrows = min(POOL_ROWS, N_NODES - row0);
    if (stripe < nrows) {   // was early-return; must not return inside mega loop
        constexpr float invN = 1.0f / N_NODES;
        float mean[4], scl[4], bb[4];
#pragma unroll
        for (int t = 0; t < 4; t++) {
            float mn = cs_sh[c4 + t] * invN;
            float var = cs_sh[128 + c4 + t] * invN - mn * mn;
            mean[t] = mn;
            scl[t] = gam[c4 + t] * rsqrtf(var + BN_EPS);
            bb[t] = bet[c4 + t];
        }
        int cur = sbatch[stripe];
        float a0 = 0, a1 = 0, a2 = 0, a3 = 0;
        for (int r = stripe; r < nrows; r += 8) {
            int g = sbatch[r];
            if (g != cur) {
                atomicAdd(&pooled_sum[cur * F_HID + c4 + 0], a0);
                atomicAdd(&pooled_sum[cur * F_HID + c4 + 1], a1);
                atomicAdd(&pooled_sum[cur * F_HID + c4 + 2], a2);
                atomicAdd(&pooled_sum[cur * F_HID + c4 + 3], a3);
                cur = g; a0 = a1 = a2 = a3 = 0.f;
            }
            uint2 v = *(const uint2*)(h + (size_t)(row0 + r) * F_HID + c4);
            a0 += fmaxf((bflo(v.x) - mean[0]) * scl[0] + bb[0], 0.f);
            a1 += fmaxf((bfhi(v.x) - mean[1]) * scl[1] + bb[1], 0.f);
            a2 += fmaxf((bflo(v.y) - mean[2]) * scl[2] + bb[2], 0.f);
            a3 += fmaxf((bfhi(v.y) - mean[3]) * scl[3] + bb[3], 0.f);
        }
        atomicAdd(&pooled_sum[cur * F_HID + c4 + 0], a0);
        atomicAdd(&pooled_sum[cur * F_HID + c4 + 1], a1);
        atomicAdd(&pooled_sum[cur * F_HID + c4 + 2], a2);
        atomicAdd(&pooled_sum[cur * F_HID + c4 + 3], a3);
    }
    __syncthreads();   // loop-reuse guard
}

__device__ void body_mlp(int vb, const float* __restrict__ pooled_sum, const int* __restrict__ batch,
                         const float* __restrict__ Wf1, const float* __restrict__ bf1,
                         const float* __restrict__ Wf2, const float* __restrict__ bf2,
                         float* __restrict__ out) {
    __shared__ float p[128];
    __shared__ float h1[256];
    __shared__ int se[2];
    int g = vb, t = threadIdx.x;
    if (t < 2) {
        int target = g + t;
        int lo = 0, hi = N_NODES;
        while (lo < hi) {
            int mid = (lo + hi) >> 1;
            if (batch[mid] < target) lo = mid + 1; else hi = mid;
        }
        se[t] = lo;
    }
    __syncthreads();
    if (t < 128) {
        float cnt = (float)(se[1] - se[0]);
        p[t] = pooled_sum[g * F_HID + t] / fmaxf(cnt, 1.0f);
    }
    __syncthreads();
    float acc = bf1[t];
#pragma unroll 8
    for (int k = 0; k < 128; k++) acc = fmaf(p[k], Wf1[k * 256 + t], acc);
    h1[t] = fmaxf(acc, 0.f);
    __syncthreads();
    if (t < 10) {
        float o = bf2[t];
#pragma unroll 8
        for (int j = 0; j < 256; j++) o = fmaf(h1[j], Wf2[j * 10 + t], o);
        out[g * 10 + t] = o;
    }
    __syncthreads();   // loop-reuse guard
}

// ================= mega kernel (cooperative, all phases) =================
__global__ __launch_bounds__(256) void mega_kernel(
        const float* x, const int* ei, const int* batch,
        const float* W1, const float* W2, const float* W3,
        const float* g1, const float* beta1, const float* g2, const float* beta2,
        const float* g3, const float* beta3,
        const float* Wf1, const float* bf1, const float* Wf2, const float* bf2,
        float* out, int* cnt, float* part1, float* part2, float* part3,
        float* pooled_sum, ushort* col, ushort* hbA, ushort* hbB,
        ushort* W1t, ushort* W2t, ushort* W3t, uint* zbase) {
    cg::grid_group grid = cg::this_grid();
    const int G = gridDim.x;
    for (int vb = blockIdx.x; vb < P0_BLOCKS; vb += G)
        body_prep(vb, W1, W2, W3, W1t, W2t, W3t, hbA, zbase);
    grid.sync();
    for (int vb = blockIdx.x; vb < P1_BLOCKS; vb += G)
        body_fillgemm(vb, ei, cnt, col, x, W1t, hbA);
    grid.sync();
    for (int vb = blockIdx.x; vb < AGG_BLOCKS; vb += G)
        body_aggregate<false>(vb, hbA, cnt, col, hbB, part1);
    grid.sync();
    for (int vb = blockIdx.x; vb < GEMM1_BLOCKS; vb += G)
        body_gemm_bn(vb, hbB, part1, g1, beta1, W2t, cnt, hbA);
    grid.sync();
    for (int vb = blockIdx.x; vb < AGG_BLOCKS; vb += G)
        body_aggregate<true>(vb, hbA, cnt, col, hbB, part2);
    grid.sync();
    for (int vb = blockIdx.x; vb < GEMM1_BLOCKS; vb += G)
        body_gemm_bn(vb, hbB, part2, g2, beta2, W3t, cnt, hbA);
    grid.sync();
    for (int vb = blockIdx.x; vb < AGG_BLOCKS; vb += G)
        body_aggregate<true>(vb, hbA, cnt, col, hbB, part3);
    grid.sync();
    for (int vb = blockIdx.x; vb < POOL_BLOCKS; vb += G)
        body_pool(vb, hbB, part3, g3, beta3, batch, pooled_sum);
    grid.sync();
    for (int vb = blockIdx.x; vb < N_GRAPHS; vb += G)
        body_mlp(vb, pooled_sum, batch, Wf1, bf1, Wf2, bf2, out);
}

// ================= fallback wrappers (old 9-dispatch path) =================
__global__ __launch_bounds__(256) void prep_k(const float* W1, const float* W2, const float* W3,
                                              ushort* W1t, ushort* W2t, ushort* W3t,
                                              ushort* hbA, uint* zbase) {
    body_prep(blockIdx.x, W1, W2, W3, W1t, W2t, W3t, hbA, zbase);
}
__global__ __launch_bounds__(256) void fillgemm_k(const int* ei, int* cnt, ushort* col,
                                                  const float* X, const ushort* Wt, ushort* C) {
    body_fillgemm(blockIdx.x, ei, cnt, col, X, Wt, C);
}
template<bool P>
__global__ __launch_bounds__(256) void agg_k(const ushort* h, const int* cnt, const ushort* col,
                                             ushort* outp, float* part) {
    body_aggregate<P>(blockIdx.x, h, cnt, col, outp, part);
}
__global__ __launch_bounds__(256) void gemm_k(const ushort* A, const float* part, const float* gam,
                                              const float* bet, const ushort* Wt, const int* cnt,
                                              ushort* C) {
    body_gemm_bn(blockIdx.x, A, part, gam, bet, Wt, cnt, C);
}
__global__ __launch_bounds__(256) void pool_k(const ushort* h, const float* part, const float* gam,
                                              const float* bet, const int* batch, float* pooled) {
    body_pool(blockIdx.x, h, part, gam, bet, batch, pooled);
}
__global__ __launch_bounds__(256) void mlp_k(const float* pooled, const int* batch,
                                             const float* Wf1, const float* bf1,
                                             const float* Wf2, const float* bf2, float* out) {
    body_mlp(blockIdx.x, pooled, batch, Wf1, bf1, Wf2, bf2, out);
}

// ---------------- host launch ----------------
extern "C" void kernel_launch(void* const* d_in, const int* in_sizes, int n_in,
                              void* d_out, int out_size, void* d_ws, size_t ws_size,
                              hipStream_t stream) {
    (void)in_sizes; (void)n_in; (void)out_size; (void)ws_size;
    const float* x     = (const float*)d_in[0];
    const int*   ei    = (const int*)d_in[1];
    const int*   batch = (const int*)d_in[2];
    const float* W1    = (const float*)d_in[3];
    const float* g1    = (const float*)d_in[5];
    const float* beta1 = (const float*)d_in[6];
    const float* W2    = (const float*)d_in[7];
    const float* g2    = (const float*)d_in[9];
    const float* beta2 = (const float*)d_in[10];
    const float* W3    = (const float*)d_in[11];
    const float* g3    = (const float*)d_in[13];
    const float* beta3 = (const float*)d_in[14];
    const float* Wf1   = (const float*)d_in[15];
    const float* bf1   = (const float*)d_in[16];
    const float* Wf2   = (const float*)d_in[17];
    const float* bf2   = (const float*)d_in[18];
    float* out = (float*)d_out;

    char* p = (char*)d_ws;
    auto alloc = [&](size_t bytes) { char* q = p; p += (bytes + 255) & ~(size_t)255; return q; };
    // --- zero region (zeroed by prep phase): cnt | part1..3 | pooled — layout must match ZWORDS ---
    char*   zbase     = p;
    int*    cnt       = (int*)   alloc((size_t)N_NODES * 4);
    float*  part1     = (float*) alloc((size_t)STATS_G * 256 * 4);
    float*  part2     = (float*) alloc((size_t)STATS_G * 256 * 4);
    float*  part3     = (float*) alloc((size_t)STATS_G * 256 * 4);
    float*  pooled_sum= (float*) alloc((size_t)N_GRAPHS * F_HID * 4);
    // --- rest ---
    ushort* col       = (ushort*)alloc((size_t)N_NODES * ROW_CAP * 2);
    ushort* hbA       = (ushort*)alloc((size_t)(N_NODES + 1) * F_HID * 2);
    ushort* hbB       = (ushort*)alloc((size_t)(N_NODES + 1) * F_HID * 2);
    ushort* W1t       = (ushort*)alloc((size_t)96  * 128 * 2);
    ushort* W2t       = (ushort*)alloc((size_t)128 * 128 * 2);
    ushort* W3t       = (ushort*)alloc((size_t)128 * 128 * 2);

    // cooperative mega-kernel: 1 dispatch replaces 10 (R10 theory: ~10us/dispatch overhead)
    int nb = 0;
    hipError_t qerr = hipOccupancyMaxActiveBlocksPerMultiprocessor(&nb, (const void*)mega_kernel, 256, 0);
    bool coop_ok = (qerr == hipSuccess && nb > 0);
    if (coop_ok) {
        int grid = nb * 256;                    // 256 CUs on MI355X; grid % 8 == 0 keeps XCD color
        if (grid > AGG_BLOCKS) grid = AGG_BLOCKS & ~7;
        void* args[] = {
            (void*)&x, (void*)&ei, (void*)&batch,
            (void*)&W1, (void*)&W2, (void*)&W3,
            (void*)&g1, (void*)&beta1, (void*)&g2, (void*)&beta2,
            (void*)&g3, (void*)&beta3,
            (void*)&Wf1, (void*)&bf1, (void*)&Wf2, (void*)&bf2,
            (void*)&out, (void*)&cnt, (void*)&part1, (void*)&part2, (void*)&part3,
            (void*)&pooled_sum, (void*)&col, (void*)&hbA, (void*)&hbB,
            (void*)&W1t, (void*)&W2t, (void*)&W3t, (void*)&zbase };
        hipError_t lerr = hipLaunchCooperativeKernel((const void*)mega_kernel, dim3(grid), dim3(256),
                                                     args, 0, stream);
        if (lerr != hipSuccess) coop_ok = false;
    }
    if (!coop_ok) {
        // fallback: verified 9-dispatch sequence (prep now also zeroes the accumulator region)
        prep_k<<<P0_BLOCKS, 256, 0, stream>>>(W1, W2, W3, W1t, W2t, W3t, hbA, (uint*)zbase);
        fillgemm_k<<<P1_BLOCKS, 256, 0, stream>>>(ei, cnt, col, x, W1t, hbA);
        agg_k<false><<<AGG_BLOCKS, 256, 0, stream>>>(hbA, cnt, col, hbB, part1);
        gemm_k<<<GEMM1_BLOCKS, 256, 0, stream>>>(hbB, part1, g1, beta1, W2t, cnt, hbA);
        agg_k<true><<<AGG_BLOCKS, 256, 0, stream>>>(hbA, cnt, col, hbB, part2);
        gemm_k<<<GEMM1_BLOCKS, 256, 0, stream>>>(hbB, part2, g2, beta2, W3t, cnt, hbA);
        agg_k<true><<<AGG_BLOCKS, 256, 0, stream>>>(hbA, cnt, col, hbB, part3);
        pool_k<<<POOL_BLOCKS, 256, 0, stream>>>(hbB, part3, g3, beta3, batch, pooled_sum);
        mlp_k<<<N_GRAPHS, 256, 0, stream>>>(pooled_sum, batch, Wf1, bf1, Wf2, bf2, out);
    }
}

// Round 13
// 320.802 us; speedup vs baseline: 2.8279x; 2.8279x over previous
//
#include <hip/hip_runtime.h>
#include <hip/hip_bf16.h>
#include <hip/hip_fp16.h>

// ---------------- problem constants (match reference) ----------------
constexpr int N_NODES  = 50000;
constexpr int N_EDGES  = 800000;
constexpr int F_HID    = 128;
constexpr int N_GRAPHS = 64;
constexpr float BN_EPS = 1e-5f;
constexpr int ROW_CAP  = 64;   // fixed CSR row capacity; deg ~ Poisson(16)
constexpr int STATS_G  = 16;   // column-stats partial groups

using short8  = __attribute__((ext_vector_type(8))) short;
using float4v = __attribute__((ext_vector_type(4))) float;
using float2v = __attribute__((ext_vector_type(2))) float;
using uint4v  = __attribute__((ext_vector_type(4))) uint;

__device__ __forceinline__ ushort f2bf(float f) {
    uint u = __float_as_uint(f);
    return (ushort)((u + 0x7fffu + ((u >> 16) & 1u)) >> 16);   // RNE
}
__device__ __forceinline__ float bflo(uint u) { return __uint_as_float(u << 16); }
__device__ __forceinline__ float bfhi(uint u) { return __uint_as_float(u & 0xffff0000u); }
__device__ __forceinline__ int sidx(int c) { return c ^ (c >> 4); }

__device__ __forceinline__ float2v unpk(uint u) {
    float2v r;
    r.x = __uint_as_float(u << 16);
    r.y = __uint_as_float(u & 0xffff0000u);
    return r;
}
__device__ __forceinline__ void pk_add(float2v &a, float2v b) {
    asm("v_pk_add_f32 %0, %1, %0" : "+v"(a) : "v"(b));
}
__device__ __forceinline__ void pk_fma(float2v &a, float2v v, float2v w) {
    asm("v_pk_fma_f32 %0, %1, %2, %0" : "+v"(a) : "v"(v), "v"(w));
}

#define SUMV(vv) \
    pk_add(a01, unpk((vv).x)); pk_add(a23, unpk((vv).y)); \
    pk_add(a45, unpk((vv).z)); pk_add(a67, unpk((vv).w));

#define ACCV(vv, w2) \
    pk_fma(a01, unpk((vv).x), w2); pk_fma(a23, unpk((vv).y), w2); \
    pk_fma(a45, unpk((vv).z), w2); pk_fma(a67, unpk((vv).w), w2);

// ---------------- prep: weight conversions + zero-row init + accumulator zeroing ----------------
// R12: hipMemsetAsync folded in as extra blocks (saves one dispatch slot; R11 mega-fusion
// REGRESSED 326->907us from occupancy-union + grid.sync cost -- dispatch-count reduction only
// pays when it doesn't constrain per-phase occupancy).
constexpr int CONVW_ELEMS  = 96 * 128 + 2 * 128 * 128;                 // 45056
constexpr int CONVW_BLOCKS = (CONVW_ELEMS + 128 + 255) / 256;          // 177
// zero region layout MUST match host alloc order/padding (256B aligned each):
// cnt(200192B) | part1(16384) | part2(16384) | part3(16384) | pooled(32768)
constexpr int ZWORDS    = (200192 + 3 * 16384 + 32768) / 4;            // 70528
constexpr int ZB_BLOCKS = (ZWORDS + 255) / 256;                        // 276
constexpr int P0_BLOCKS = CONVW_BLOCKS + ZB_BLOCKS;                    // 453

__global__ __launch_bounds__(256) void prep_kernel(const float* __restrict__ W1, const float* __restrict__ W2,
                                                   const float* __restrict__ W3,
                                                   ushort* __restrict__ W1t, ushort* __restrict__ W2t,
                                                   ushort* __restrict__ W3t, ushort* __restrict__ hbA,
                                                   uint* __restrict__ zbase) {
    if (blockIdx.x < CONVW_BLOCKS) {
        int i = blockIdx.x * 256 + threadIdx.x;
        constexpr int S1 = 96 * 128, S2 = S1 + 128 * 128, S3 = S2 + 128 * 128;
        if (i < S1) {
            int n = i & 127, k = i >> 7;
            W1t[n * 96 + k] = f2bf(W1[i]);
        } else if (i < S2) {
            int j = i - S1, n = j & 127, k = j >> 7;
            W2t[n * 128 + k] = f2bf(W2[j]);
        } else if (i < S3) {
            int j = i - S2, n = j & 127, k = j >> 7;
            W3t[n * 128 + k] = f2bf(W3[j]);
        } else if (i < S3 + 128) {
            hbA[(size_t)N_NODES * F_HID + (i - S3)] = 0;   // dedicated zero row for masked gathers
        }
    } else {
        int j = (blockIdx.x - CONVW_BLOCKS) * 256 + (int)threadIdx.x;
        if (j < ZWORDS) zbase[j] = 0;
    }
}

// ---------------- merged fill | layer-1 MFMA GEMM ----------------
constexpr int GEMM1_BLOCKS = (N_NODES + 63) / 64;       // 782
constexpr int FILL_SLABS   = (N_EDGES + 1023) / 1024;   // 782 (1024 edges per slab)
constexpr int FILL_BLOCKS  = FILL_SLABS * 8;            // 6256 (8 colors)

__global__ __launch_bounds__(256) void fillgemm_kernel(const int* __restrict__ ei,
                                                       int* __restrict__ cnt, ushort* __restrict__ col,
                                                       const float* __restrict__ X, const ushort* __restrict__ Wt,
                                                       ushort* __restrict__ C) {
    if (blockIdx.x < GEMM1_BLOCKS) {
        // ---- layer-1 GEMM: C[N,128] = bf16(X[N,96]) @ W ----
        constexpr int K = 96, KSTEPS = 3;
        int wave = threadIdx.x >> 6, lane = threadIdx.x & 63;
        int m = lane & 15, quad = lane >> 4;
        int row_base = blockIdx.x * 64 + wave * 16;
        short8 afrag[KSTEPS];
        int arow = min(row_base + m, N_NODES - 1);
#pragma unroll
        for (int ks = 0; ks < KSTEPS; ks++) {
            const float* src = X + (size_t)arow * K + ks * 32 + quad * 8;
            float4 a0 = *(const float4*)src;
            float4 a1 = *(const float4*)(src + 4);
            afrag[ks][0] = (short)f2bf(a0.x); afrag[ks][1] = (short)f2bf(a0.y);
            afrag[ks][2] = (short)f2bf(a0.z); afrag[ks][3] = (short)f2bf(a0.w);
            afrag[ks][4] = (short)f2bf(a1.x); afrag[ks][5] = (short)f2bf(a1.y);
            afrag[ks][6] = (short)f2bf(a1.z); afrag[ks][7] = (short)f2bf(a1.w);
        }
#pragma unroll
        for (int nt = 0; nt < 8; nt++) {
            float4v acc = {0.f, 0.f, 0.f, 0.f};
            const ushort* wbase = Wt + (size_t)(nt * 16 + m) * K + quad * 8;
#pragma unroll
            for (int ks = 0; ks < KSTEPS; ks++) {
                short8 bfrag = *(const short8*)(wbase + ks * 32);
                acc = __builtin_amdgcn_mfma_f32_16x16x32_bf16(afrag[ks], bfrag, acc, 0, 0, 0);
            }
            int colg = nt * 16 + m;
#pragma unroll
            for (int r = 0; r < 4; r++) {
                int rowg = row_base + quad * 4 + r;
                if (rowg < N_NODES) C[(size_t)rowg * F_HID + colg] = f2bf(acc[r]);
            }
        }
    } else {
        // ---- CSR fill, color-filtered, 4 edges/thread ----
        int fb    = blockIdx.x - GEMM1_BLOCKS;
        int color = blockIdx.x & 7;          // absolute blockIdx -> matches XCD round-robin
        int slab  = fb >> 3;
        int i0 = slab * 1024 + threadIdx.x * 4;
        if (i0 >= N_EDGES) return;           // E % 4 == 0 -> all 4 valid when i0 < E
        int4 dv = *(const int4*)(ei + N_EDGES + i0);
        int4 sv = *(const int4*)(ei + i0);
#pragma unroll
        for (int k = 0; k < 4; k++) {
            int d = (&dv.x)[k];
            if ((d & 7) != color) continue;
            int s = (&sv.x)[k];
            int pos = atomicAdd(&cnt[d], 1);
            if (pos < ROW_CAP) col[(size_t)d * ROW_CAP + pos] = (ushort)s;
        }
    }
}

// ---------------- MFMA transform, fused BN+ReLU on A, dinv-scaled output rows ----------------
__global__ __launch_bounds__(256) void mfma_gemm_bn_kernel(const ushort* __restrict__ A, const float* __restrict__ part,
                                                           const float* __restrict__ gam, const float* __restrict__ bet,
                                                           const ushort* __restrict__ Wt, const int* __restrict__ cnt,
                                                           ushort* __restrict__ C) {
    __shared__ float cs_sh[256];
    {
        int t = threadIdx.x;
        float v = 0.f;
#pragma unroll
        for (int g2 = 0; g2 < STATS_G; g2++) v += part[g2 * 256 + sidx(t & 127) + (t & 128)];
        cs_sh[t] = v;
    }
    __syncthreads();

    constexpr int K = 128, KSTEPS = 4;
    int wave = threadIdx.x >> 6, lane = threadIdx.x & 63;
    int m = lane & 15, quad = lane >> 4;
    int row_base = blockIdx.x * 64 + wave * 16;
    int arow = min(row_base + m, N_NODES - 1);
    constexpr float invN = 1.0f / N_NODES;

    float dinv4[4];
#pragma unroll
    for (int r = 0; r < 4; r++) {
        int rg = min(row_base + quad * 4 + r, N_NODES - 1);
        dinv4[r] = rsqrtf((float)(cnt[rg] + 1));
    }

    short8 afrag[KSTEPS];
#pragma unroll
    for (int ks = 0; ks < KSTEPS; ks++) {
        int k0 = ks * 32 + quad * 8;
        uint4 av = *(const uint4*)(A + (size_t)arow * K + k0);
        float vals[8] = {bflo(av.x), bfhi(av.x), bflo(av.y), bfhi(av.y),
                         bflo(av.z), bfhi(av.z), bflo(av.w), bfhi(av.w)};
#pragma unroll
        for (int jj = 0; jj < 8; jj += 4) {
            float4 gv = *(const float4*)(gam + k0 + jj);
            float4 bv = *(const float4*)(bet + k0 + jj);
            const float* g = (const float*)&gv; const float* b = (const float*)&bv;
#pragma unroll
            for (int t = 0; t < 4; t++) {
                int kc = k0 + jj + t;
                float mean = cs_sh[kc] * invN;
                float var  = cs_sh[128 + kc] * invN - mean * mean;
                float sc   = g[t] * rsqrtf(var + BN_EPS);
                float val  = fmaxf((vals[jj + t] - mean) * sc + b[t], 0.0f);
                afrag[ks][jj + t] = (short)f2bf(val);
            }
        }
    }

#pragma unroll
    for (int nt = 0; nt < 8; nt++) {
        float4v acc = {0.f, 0.f, 0.f, 0.f};
        const ushort* wbase = Wt + (size_t)(nt * 16 + m) * K + quad * 8;
#pragma unroll
        for (int ks = 0; ks < KSTEPS; ks++) {
            short8 bfrag = *(const short8*)(wbase + ks * 32);
            acc = __builtin_amdgcn_mfma_f32_16x16x32_bf16(afrag[ks], bfrag, acc, 0, 0, 0);
        }
        int colg = nt * 16 + m;
#pragma unroll
        for (int r = 0; r < 4; r++) {
            int rowg = row_base + quad * 4 + r;
            if (rowg < N_NODES) C[(size_t)rowg * F_HID + colg] = f2bf(acc[r] * dinv4[r]);
        }
    }
}

// ---------------- sparse aggregation: one wave per dst row + fused column stats ----------------
// R9-verified: wave-uniform group gating (interleaved slots, s_cbranch skips dead groups);
// all gathers issued unconditionally (ZR-masked) in round 1 -> 2-round latency chain intact.
template<bool PRESCALED>
__global__ __launch_bounds__(256) void aggregate_kernel(const ushort* __restrict__ h, const int* __restrict__ cnt,
                                                        const ushort* __restrict__ col, ushort* __restrict__ outp,
                                                        float* __restrict__ part) {
    __shared__ float sh_s[4][128];
    __shared__ float sh_q[4][128];
    int wv   = (blockIdx.x * 256 + (int)threadIdx.x) >> 6;
    int wave = threadIdx.x >> 6;
    int lane = threadIdx.x & 63;
    int q  = lane >> 4;
    int sl = lane & 15;
    const ushort* crow = col + (size_t)wv * ROW_CAP;
    constexpr int ZR = N_NODES;

    int deg = cnt[wv];
    uint4 R0 = *(const uint4*)(crow);
    uint4 R1 = *(const uint4*)(crow + 8);
    uint4 R2 = *(const uint4*)(crow + 16);
    uint4 R3 = *(const uint4*)(crow + 24);
    uint4 selfv = *(const uint4*)(h + (size_t)wv * F_HID + sl * 8);

    int len = min(deg, ROW_CAP);
    float dinv_d = rsqrtf((float)(deg + 1));
    float2v a01 = {0.f, 0.f}, a23 = {0.f, 0.f}, a45 = {0.f, 0.f}, a67 = {0.f, 0.f};

    if (len <= 32) {
        int  sh16 = (q & 1) << 4;
        bool qhi  = (q & 2) != 0;
        uint pp0 = qhi ? R0.y : R0.x;  uint pp1 = qhi ? R0.w : R0.z;
        uint pp2 = qhi ? R1.y : R1.x;  uint pp3 = qhi ? R1.w : R1.z;
        uint pp4 = qhi ? R2.y : R2.x;  uint pp5 = qhi ? R2.w : R2.z;
        uint pp6 = qhi ? R3.y : R3.x;  uint pp7 = qhi ? R3.w : R3.z;
        int rec0 = (int)((pp0 >> sh16) & 0xffffu);
        int rec1 = (int)((pp1 >> sh16) & 0xffffu);
        int rec2 = (int)((pp2 >> sh16) & 0xffffu);
        int rec3 = (int)((pp3 >> sh16) & 0xffffu);
        int rec4 = (int)((pp4 >> sh16) & 0xffffu);
        int rec5 = (int)((pp5 >> sh16) & 0xffffu);
        int rec6 = (int)((pp6 >> sh16) & 0xffffu);
        int rec7 = (int)((pp7 >> sh16) & 0xffffu);
        int r0 = (q      < len) ? rec0 : ZR;
        int r1 = (q + 4  < len) ? rec1 : ZR;
        int r2 = (q + 8  < len) ? rec2 : ZR;
        int r3 = (q + 12 < len) ? rec3 : ZR;
        int r4 = (q + 16 < len) ? rec4 : ZR;
        int r5 = (q + 20 < len) ? rec5 : ZR;
        int r6 = (q + 24 < len) ? rec6 : ZR;
        int r7 = (q + 28 < len) ? rec7 : ZR;
        uint4v v0 = *(const uint4v*)(h + (size_t)r0 * F_HID + sl * 8);
        uint4v v1 = *(const uint4v*)(h + (size_t)r1 * F_HID + sl * 8);
        uint4v v2 = *(const uint4v*)(h + (size_t)r2 * F_HID + sl * 8);
        uint4v v3 = *(const uint4v*)(h + (size_t)r3 * F_HID + sl * 8);
        uint4v v4 = *(const uint4v*)(h + (size_t)r4 * F_HID + sl * 8);
        uint4v v5 = *(const uint4v*)(h + (size_t)r5 * F_HID + sl * 8);
        uint4v v6 = *(const uint4v*)(h + (size_t)r6 * F_HID + sl * 8);
        uint4v v7 = *(const uint4v*)(h + (size_t)r7 * F_HID + sl * 8);
        if constexpr (PRESCALED) {
            asm volatile("" : "+v"(v0), "+v"(v1), "+v"(v2), "+v"(v3));
            asm volatile("" : "+v"(v4), "+v"(v5), "+v"(v6), "+v"(v7));
            int slen = __builtin_amdgcn_readfirstlane(len);
            if (q == 0) { SUMV(selfv) }
            if (slen > 0)  { SUMV(v0) }
            if (slen > 4)  { SUMV(v1) }
            if (slen > 8)  { SUMV(v2) }
            if (slen > 12) { SUMV(v3) }
            if (slen > 16) { SUMV(v4) }
            if (slen > 20) { SUMV(v5) }
            if (slen > 24) { SUMV(v6) }
            if (slen > 28) { SUMV(v7) }
        } else {
            int c0 = cnt[r0]; int c1 = cnt[r1]; int c2 = cnt[r2]; int c3 = cnt[r3];
            int c4 = cnt[r4]; int c5 = cnt[r5]; int c6 = cnt[r6]; int c7 = cnt[r7];
            asm volatile("" : "+v"(v0), "+v"(v1), "+v"(v2), "+v"(v3));
            asm volatile("" : "+v"(v4), "+v"(v5), "+v"(v6), "+v"(v7));
            asm volatile("" : "+v"(c0), "+v"(c1), "+v"(c2), "+v"(c3),
                             "+v"(c4), "+v"(c5), "+v"(c6), "+v"(c7));
            int slen = __builtin_amdgcn_readfirstlane(len);
            if (q == 0) { float sw = dinv_d * dinv_d; float2v sw2 = {sw, sw}; ACCV(selfv, sw2) }
            if (slen > 0)  { float w = (q      < len) ? rsqrtf((float)(c0 + 1)) * dinv_d : 0.f; float2v w2 = {w, w}; ACCV(v0, w2) }
            if (slen > 4)  { float w = (q + 4  < len) ? rsqrtf((float)(c1 + 1)) * dinv_d : 0.f; float2v w2 = {w, w}; ACCV(v1, w2) }
            if (slen > 8)  { float w = (q + 8  < len) ? rsqrtf((float)(c2 + 1)) * dinv_d : 0.f; float2v w2 = {w, w}; ACCV(v2, w2) }
            if (slen > 12) { float w = (q + 12 < len) ? rsqrtf((float)(c3 + 1)) * dinv_d : 0.f; float2v w2 = {w, w}; ACCV(v3, w2) }
            if (slen > 16) { float w = (q + 16 < len) ? rsqrtf((float)(c4 + 1)) * dinv_d : 0.f; float2v w2 = {w, w}; ACCV(v4, w2) }
            if (slen > 20) { float w = (q + 20 < len) ? rsqrtf((float)(c5 + 1)) * dinv_d : 0.f; float2v w2 = {w, w}; ACCV(v5, w2) }
            if (slen > 24) { float w = (q + 24 < len) ? rsqrtf((float)(c6 + 1)) * dinv_d : 0.f; float2v w2 = {w, w}; ACCV(v6, w2) }
            if (slen > 28) { float w = (q + 28 < len) ? rsqrtf((float)(c7 + 1)) * dinv_d : 0.f; float2v w2 = {w, w}; ACCV(v7, w2) }
        }
    } else {
        if (PRESCALED) {
            if (q == 0) { SUMV(selfv) }
        } else if (q == 0) {
            float sw = dinv_d * dinv_d; float2v sw2 = {sw, sw}; ACCV(selfv, sw2)
        }
        int base = 0;
        for (; base + 16 <= len; base += 16) {
            int r0 = crow[base + q];
            int r1 = crow[base + 4 + q];
            int r2 = crow[base + 8 + q];
            int r3 = crow[base + 12 + q];
            uint4 v0 = *(const uint4*)(h + (size_t)r0 * F_HID + sl * 8);
            uint4 v1 = *(const uint4*)(h + (size_t)r1 * F_HID + sl * 8);
            uint4 v2 = *(const uint4*)(h + (size_t)r2 * F_HID + sl * 8);
            uint4 v3 = *(const uint4*)(h + (size_t)r3 * F_HID + sl * 8);
            if (PRESCALED) {
                SUMV(v0) SUMV(v1) SUMV(v2) SUMV(v3)
            } else {
                float w0 = rsqrtf((float)(cnt[r0] + 1)) * dinv_d;
                float w1 = rsqrtf((float)(cnt[r1] + 1)) * dinv_d;
                float w2 = rsqrtf((float)(cnt[r2] + 1)) * dinv_d;
                float w3 = rsqrtf((float)(cnt[r3] + 1)) * dinv_d;
                { float2v w2v = {w0, w0}; ACCV(v0, w2v) }
                { float2v w2v = {w1, w1}; ACCV(v1, w2v) }
                { float2v w2v = {w2, w2}; ACCV(v2, w2v) }
                { float2v w2v = {w3, w3}; ACCV(v3, w2v) }
            }
        }
        if (base < len) {
            int i0t = base + q, i1t = base + 4 + q, i2t = base + 8 + q, i3t = base + 12 + q;
            int r0 = (i0t < len) ? (int)crow[i0t] : ZR;
            int r1 = (i1t < len) ? (int)crow[i1t] : ZR;
            int r2 = (i2t < len) ? (int)crow[i2t] : ZR;
            int r3 = (i3t < len) ? (int)crow[i3t] : ZR;
            uint4 v0 = *(const uint4*)(h + (size_t)r0 * F_HID + sl * 8);
            uint4 v1 = *(const uint4*)(h + (size_t)r1 * F_HID + sl * 8);
            uint4 v2 = *(const uint4*)(h + (size_t)r2 * F_HID + sl * 8);
            uint4 v3 = *(const uint4*)(h + (size_t)r3 * F_HID + sl * 8);
            if (PRESCALED) {
                SUMV(v0) SUMV(v1) SUMV(v2) SUMV(v3)
            } else {
                float w0 = (i0t < len) ? rsqrtf((float)(cnt[r0] + 1)) * dinv_d : 0.f;
                float w1 = (i1t < len) ? rsqrtf((float)(cnt[r1] + 1)) * dinv_d : 0.f;
                float w2 = (i2t < len) ? rsqrtf((float)(cnt[r2] + 1)) * dinv_d : 0.f;
                float w3 = (i3t < len) ? rsqrtf((float)(cnt[r3] + 1)) * dinv_d : 0.f;
                { float2v w2v = {w0, w0}; ACCV(v0, w2v) }
                { float2v w2v = {w1, w1}; ACCV(v1, w2v) }
                { float2v w2v = {w2, w2}; ACCV(v2, w2v) }
                { float2v w2v = {w3, w3}; ACCV(v3, w2v) }
            }
        }
    }
    float a0 = a01.x, a1 = a01.y, a2 = a23.x, a3 = a23.y;
    float a4 = a45.x, a5 = a45.y, a6 = a67.x, a7 = a67.y;
    a0 += __shfl_down(a0, 16); a1 += __shfl_down(a1, 16); a2 += __shfl_down(a2, 16); a3 += __shfl_down(a3, 16);
    a4 += __shfl_down(a4, 16); a5 += __shfl_down(a5, 16); a6 += __shfl_down(a6, 16); a7 += __shfl_down(a7, 16);
    a0 += __shfl_down(a0, 32); a1 += __shfl_down(a1, 32); a2 += __shfl_down(a2, 32); a3 += __shfl_down(a3, 32);
    a4 += __shfl_down(a4, 32); a5 += __shfl_down(a5, 32); a6 += __shfl_down(a6, 32); a7 += __shfl_down(a7, 32);
    if (q == 0) {
        if (PRESCALED) {
            a0 *= dinv_d; a1 *= dinv_d; a2 *= dinv_d; a3 *= dinv_d;
            a4 *= dinv_d; a5 *= dinv_d; a6 *= dinv_d; a7 *= dinv_d;
        }
        uint4 o;
        o.x = (uint)f2bf(a0) | ((uint)f2bf(a1) << 16);
        o.y = (uint)f2bf(a2) | ((uint)f2bf(a3) << 16);
        o.z = (uint)f2bf(a4) | ((uint)f2bf(a5) << 16);
        o.w = (uint)f2bf(a6) | ((uint)f2bf(a7) << 16);
        *(uint4*)(outp + (size_t)wv * F_HID + sl * 8) = o;
        int c0 = sl * 8;
        sh_s[wave][sidx(c0 + 0)] = a0; sh_q[wave][sidx(c0 + 0)] = a0 * a0;
        sh_s[wave][sidx(c0 + 1)] = a1; sh_q[wave][sidx(c0 + 1)] = a1 * a1;
        sh_s[wave][sidx(c0 + 2)] = a2; sh_q[wave][sidx(c0 + 2)] = a2 * a2;
        sh_s[wave][sidx(c0 + 3)] = a3; sh_q[wave][sidx(c0 + 3)] = a3 * a3;
        sh_s[wave][sidx(c0 + 4)] = a4; sh_q[wave][sidx(c0 + 4)] = a4 * a4;
        sh_s[wave][sidx(c0 + 5)] = a5; sh_q[wave][sidx(c0 + 5)] = a5 * a5;
        sh_s[wave][sidx(c0 + 6)] = a6; sh_q[wave][sidx(c0 + 6)] = a6 * a6;
        sh_s[wave][sidx(c0 + 7)] = a7; sh_q[wave][sidx(c0 + 7)] = a7 * a7;
    }
    __syncthreads();
    int t = threadIdx.x;
    int cc = sidx(t & 127);
    float v = (t < 128) ? (sh_s[0][cc] + sh_s[1][cc] + sh_s[2][cc] + sh_s[3][cc])
                        : (sh_q[0][cc] + sh_q[1][cc] + sh_q[2][cc] + sh_q[3][cc]);
    atomicAdd(&part[(blockIdx.x & (STATS_G - 1)) * 256 + (t & 128) + cc], v);
}

// ---------------- fused layer-3 BN+ReLU + graph pooling (bf16 in, partial-stats in) ----------------
constexpr int POOL_ROWS = 128;
constexpr int POOL_BLOCKS = (N_NODES + POOL_ROWS - 1) / POOL_ROWS;     // 391
__global__ __launch_bounds__(256) void pool_bn_kernel(const ushort* __restrict__ h, const float* __restrict__ part,
                                                      const float* __restrict__ gam, const float* __restrict__ bet,
                                                      const int* __restrict__ batch, float* __restrict__ pooled_sum) {
    __shared__ float cs_sh[256];
    __shared__ int sbatch[POOL_ROWS];
    int row0 = blockIdx.x * POOL_ROWS;
    {
        int t = threadIdx.x;
        float v = 0.f;
#pragma unroll
        for (int g2 = 0; g2 < STATS_G; g2++) v += part[g2 * 256 + sidx(t & 127) + (t & 128)];
        cs_sh[t] = v;
    }
    if (threadIdx.x < POOL_ROWS) {
        int r = row0 + threadIdx.x;
        sbatch[threadIdx.x] = (r < N_NODES) ? batch[r] : -1;
    }
    __syncthreads();
    int c4 = (threadIdx.x & 31) * 4;
    int stripe = threadIdx.x >> 5;   // 0..7
    int nrows = min(POOL_ROWS, N_NODES - row0);
    if (stripe >= nrows) return;
    constexpr float invN = 1.0f / N_NODES;
    float mean[4], scl[4], bb[4];
#pragma unroll
    for (int t = 0; t < 4; t++) {
        float mn = cs_sh[c4 + t] * invN;
        float var = cs_sh[128 + c4 + t] * invN - mn * mn;
        mean[t] = mn;
        scl[t] = gam[c4 + t] * rsqrtf(var + BN_EPS);
        bb[t] = bet[c4 + t];
    }
    int cur = sbatch[stripe];
    float a0 = 0, a1 = 0, a2 = 0, a3 = 0;
    for (int r = stripe; r < nrows; r += 8) {
        int g = sbatch[r];
        if (g != cur) {
            atomicAdd(&pooled_sum[cur * F_HID + c4 + 0], a0);
            atomicAdd(&pooled_sum[cur * F_HID + c4 + 1], a1);
            atomicAdd(&pooled_sum[cur * F_HID + c4 + 2], a2);
            atomicAdd(&pooled_sum[cur * F_HID + c4 + 3], a3);
            cur = g; a0 = a1 = a2 = a3 = 0.f;
        }
        uint2 v = *(const uint2*)(h + (size_t)(row0 + r) * F_HID + c4);
        a0 += fmaxf((bflo(v.x) - mean[0]) * scl[0] + bb[0], 0.f);
        a1 += fmaxf((bfhi(v.x) - mean[1]) * scl[1] + bb[1], 0.f);
        a2 += fmaxf((bflo(v.y) - mean[2]) * scl[2] + bb[2], 0.f);
        a3 += fmaxf((bfhi(v.y) - mean[3]) * scl[3] + bb[3], 0.f);
    }
    atomicAdd(&pooled_sum[cur * F_HID + c4 + 0], a0);
    atomicAdd(&pooled_sum[cur * F_HID + c4 + 1], a1);
    atomicAdd(&pooled_sum[cur * F_HID + c4 + 2], a2);
    atomicAdd(&pooled_sum[cur * F_HID + c4 + 3], a3);
}

// ---------------- MLP head (boundary search + divide-by-count folded in) ----------------
__global__ __launch_bounds__(256) void mlp_kernel(const float* __restrict__ pooled_sum, const int* __restrict__ batch,
                                                  const float* __restrict__ Wf1, const float* __restrict__ bf1,
                                                  const float* __restrict__ Wf2, const float* __restrict__ bf2,
                                                  float* __restrict__ out) {
    __shared__ float p[128];
    __shared__ float h1[256];
    __shared__ int se[2];
    int g = blockIdx.x, t = threadIdx.x;
    if (t < 2) {   // lower_bound(batch, g + t)
        int target = g + t;
        int lo = 0, hi = N_NODES;
        while (lo < hi) {
            int mid = (lo + hi) >> 1;
            if (batch[mid] < target) lo = mid + 1; else hi = mid;
        }
        se[t] = lo;
    }
    __syncthreads();
    if (t < 128) {
        float cnt = (float)(se[1] - se[0]);
        p[t] = pooled_sum[g * F_HID + t] / fmaxf(cnt, 1.0f);
    }
    __syncthreads();
    float acc = bf1[t];
#pragma unroll 8
    for (int k = 0; k < 128; k++) acc = fmaf(p[k], Wf1[k * 256 + t], acc);
    h1[t] = fmaxf(acc, 0.f);
    __syncthreads();
    if (t < 10) {
        float o = bf2[t];
#pragma unroll 8
        for (int j = 0; j < 256; j++) o = fmaf(h1[j], Wf2[j * 10 + t], o);
        out[g * 10 + t] = o;
    }
}

// ---------------- host launch ----------------
extern "C" void kernel_launch(void* const* d_in, const int* in_sizes, int n_in,
                              void* d_out, int out_size, void* d_ws, size_t ws_size,
                              hipStream_t stream) {
    (void)in_sizes; (void)n_in; (void)out_size; (void)ws_size;
    const float* x     = (const float*)d_in[0];
    const int*   ei    = (const int*)d_in[1];
    const int*   batch = (const int*)d_in[2];
    const float* W1    = (const float*)d_in[3];
    const float* g1    = (const float*)d_in[5];
    const float* beta1 = (const float*)d_in[6];
    const float* W2    = (const float*)d_in[7];
    const float* g2    = (const float*)d_in[9];
    const float* beta2 = (const float*)d_in[10];
    const float* W3    = (const float*)d_in[11];
    const float* g3    = (const float*)d_in[13];
    const float* beta3 = (const float*)d_in[14];
    const float* Wf1   = (const float*)d_in[15];
    const float* bf1   = (const float*)d_in[16];
    const float* Wf2   = (const float*)d_in[17];
    const float* bf2   = (const float*)d_in[18];
    float* out = (float*)d_out;

    char* p = (char*)d_ws;
    auto alloc = [&](size_t bytes) { char* q = p; p += (bytes + 255) & ~(size_t)255; return q; };
    // --- zero region (zeroed inside prep_kernel): cnt | part1..3 | pooled — layout must match ZWORDS ---
    // NOTE: part1 must directly follow cnt (cnt[ZR] aliases part1[0]; masked lanes discard via w=0).
    char*   zbase     = p;
    int*    cnt       = (int*)   alloc((size_t)N_NODES * 4);
    float*  part1     = (float*) alloc((size_t)STATS_G * 256 * 4);
    float*  part2     = (float*) alloc((size_t)STATS_G * 256 * 4);
    float*  part3     = (float*) alloc((size_t)STATS_G * 256 * 4);
    float*  pooled_sum= (float*) alloc((size_t)N_GRAPHS * F_HID * 4);
    // --- rest (col never needs zeroing: reads bounded by cnt/ZR-select) ---
    ushort* col       = (ushort*)alloc((size_t)N_NODES * ROW_CAP * 2);       // 6.4 MB fixed-cap CSR
    ushort* hbA       = (ushort*)alloc((size_t)(N_NODES + 1) * F_HID * 2);   // gemm out + zero row
    ushort* hbB       = (ushort*)alloc((size_t)(N_NODES + 1) * F_HID * 2);   // agg out + zero row
    ushort* W1t       = (ushort*)alloc((size_t)96  * 128 * 2);
    ushort* W2t       = (ushort*)alloc((size_t)128 * 128 * 2);
    ushort* W3t       = (ushort*)alloc((size_t)128 * 128 * 2);

    // 1. weight conversions + zero-row init + accumulator zeroing (memset folded in; 9 dispatches total)
    prep_kernel<<<P0_BLOCKS, 256, 0, stream>>>(W1, W2, W3, W1t, W2t, W3t, hbA, (uint*)zbase);
    // 2. CSR fill (XCD-color partitioned, 4 edges/thread) overlapped with layer-1 GEMM
    fillgemm_kernel<<<GEMM1_BLOCKS + FILL_BLOCKS, 256, 0, stream>>>(ei, cnt, col, x, W1t, hbA);
    // layer 1: weighted aggregate + fused stats
    aggregate_kernel<false><<<N_NODES / 4, 256, 0, stream>>>(hbA, cnt, col, hbB, part1);
    // layer 2: BN+ReLU+GEMM (output rows pre-scaled by dinv) -> unweighted aggregate
    mfma_gemm_bn_kernel<<<GEMM1_BLOCKS, 256, 0, stream>>>(hbB, part1, g1, beta1, W2t, cnt, hbA);
    aggregate_kernel<true><<<N_NODES / 4, 256, 0, stream>>>(hbA, cnt, col, hbB, part2);
    // layer 3
    mfma_gemm_bn_kernel<<<GEMM1_BLOCKS, 256, 0, stream>>>(hbB, part2, g2, beta2, W3t, cnt, hbA);
    aggregate_kernel<true><<<N_NODES / 4, 256, 0, stream>>>(hbA, cnt, col, hbB, part3);
    // fused BN+ReLU+pool, then MLP head
    pool_bn_kernel<<<POOL_BLOCKS, 256, 0, stream>>>(hbB, part3, g3, beta3, batch, pooled_sum);
    mlp_kernel<<<N_GRAPHS, 256, 0, stream>>>(pooled_sum, batch, Wf1, bf1, Wf2, bf2, out);
}